// Round 10
// baseline (216.228 us; speedup 1.0000x reference)
//
#include <hip/hip_runtime.h>
#include <hip/hip_fp16.h>

#define N_NODES 100000
#define N_EDGES 1600000
#define IN_F 128
#define HID_F 64
#define CLS_F 32

#define NBKT 512                 // buckets of 196 dst nodes each
#define BKT_NODES 196
#define NBLK 800                 // edge partition blocks (3.1 blocks/CU)
#define EPB 2000                 // edges per partition block (800*2000 = 1.6M exact)
#define CAPB_RAW 4096            // fixed raw staging region per bucket (mean 3136, +17 sigma)
#define CAPB 5120                // fixed padded csr region per bucket (mean ~3800, >20 sigma)
#define XW_BLOCKS 1563           // ceil(100001 / 64) node-GEMM blocks

typedef short s8v __attribute__((ext_vector_type(8)));
typedef float f4v __attribute__((ext_vector_type(4)));
typedef _Float16 h2v __attribute__((ext_vector_type(2)));

__device__ __forceinline__ unsigned short f2h(float f) {
    return __half_as_ushort(__float2half_rn(f));
}
__device__ __forceinline__ int packh2(float x, float y) {
    __half2 p = __floats2half2_rn(x, y);
    union { __half2 h; int i; } c; c.h = p; return c.i;
}

// acc[j] += dv * (float)h16[j]  -- compiles to v_fma_mix_f32 (1 instr/feat)
__device__ __forceinline__ void mix8(float* a, int4 v, float dv) {
    union { int4 i; __half h[8]; } c; c.i = v;
#pragma unroll
    for (int j = 0; j < 8; j++)
        a[j] = fmaf(__half2float(c.h[j]), dv, a[j]);
}

// s += dot(h2, w2) with f32 accumulate
__device__ __forceinline__ float fdot2acc(unsigned hu, unsigned wu, float s) {
#if __has_builtin(__builtin_amdgcn_fdot2)
    union { unsigned u; h2v h; } a, b;
    a.u = hu; b.u = wu;
    return __builtin_amdgcn_fdot2(a.h, b.h, s, false);
#else
    union { unsigned u; __half2 h; } a, b;
    a.u = hu; b.u = wu;
    float2 fa = __half22float2(a.h), fb = __half22float2(b.h);
    return s + fa.x * fb.x + fa.y * fb.y;
#endif
}

// gather2 accumulate: 1 fdot2 per feat
__device__ __forceinline__ void dot4(float* a, int2 v) {
#if __has_builtin(__builtin_amdgcn_fdot2)
    union { int2 i; h2v h[2]; } c; c.i = v;
    const h2v E0 = {(_Float16)1.f, (_Float16)0.f};
    const h2v E1 = {(_Float16)0.f, (_Float16)1.f};
#pragma unroll
    for (int j = 0; j < 2; j++) {
        a[2 * j]     = __builtin_amdgcn_fdot2(c.h[j], E0, a[2 * j], false);
        a[2 * j + 1] = __builtin_amdgcn_fdot2(c.h[j], E1, a[2 * j + 1], false);
    }
#else
    union { int2 i; __half2 h[2]; } c; c.i = v;
#pragma unroll
    for (int j = 0; j < 2; j++) {
        float2 f = __half22float2(c.h[j]);
        a[2 * j] += f.x; a[2 * j + 1] += f.y;
    }
#endif
}

// ---------------------------------------------------------------------------
// CSR build (round-6 verbatim). cursor[] holds per-bucket COUNTS (memset 0);
// staging regions fixed at b*CAPB_RAW. One fused scatter kernel.
// ---------------------------------------------------------------------------

__global__ __launch_bounds__(256) void bucket_scatter_kernel(
        const int* __restrict__ src, const int* __restrict__ dst,
        int* __restrict__ cursor, unsigned* __restrict__ bkt) {
    __shared__ int h[NBKT];
    __shared__ int base[NBKT];
    __shared__ int lcur[NBKT];
    __shared__ unsigned pkS[EPB];
    __shared__ short gS[EPB];
    int t = threadIdx.x;
    for (int i = t; i < NBKT; i += 256) { h[i] = 0; lcur[i] = 0; }
    __syncthreads();

    int e0 = blockIdx.x * EPB;
    for (int i = t; i < EPB; i += 256) {
        int e = e0 + i;
        int d = dst[e];
        int g = d / BKT_NODES;
        pkS[i] = ((unsigned)(d - g * BKT_NODES) << 17) | (unsigned)src[e];
        gS[i] = (short)g;
        atomicAdd(&h[g], 1);
    }
    __syncthreads();

    for (int g = t; g < NBKT; g += 256)
        if (h[g] > 0) base[g] = g * CAPB_RAW + atomicAdd(&cursor[g], h[g]);
    __syncthreads();

    for (int i = t; i < EPB; i += 256) {
        int g = gS[i];
        int p = base[g] + atomicAdd(&lcur[g], 1);
        bkt[p] = pkS[i];
    }
}

// ---------------------------------------------------------------------------
// Fused: blocks [0,NBKT) = per-bucket counting sort; blocks [NBKT, ...) =
// y1 = x @ W1 via MFMA f16 (RAW — gather1 folds dinv[src] per edge).
// (round-6 verbatim)
// ---------------------------------------------------------------------------
#define XBM 64
#define SMEM_BYTES 33792

__device__ __forceinline__ void sort_body(char* smem, int b,
        const int* __restrict__ cursor, const unsigned* __restrict__ bkt,
        int* __restrict__ csr, int* __restrict__ off, int* __restrict__ endp,
        float* __restrict__ dinv) {
    int* hist  = (int*)smem;                    // 196
    int* loff  = hist + BKT_NODES;              // 196
    int* loffB = loff + BKT_NODES;              // 196
    int* wt    = loffB + BKT_NODES;             // 4
    int* csrS  = wt + 4;                        // 5120
    int t = threadIdx.x;
    int s0 = b * CAPB_RAW;
    int nE = cursor[b];                         // raw bucket size

    for (int i = t; i < BKT_NODES; i += 256) hist[i] = 0;
    __syncthreads();
    for (int i = t; i < nE; i += 256)
        atomicAdd(&hist[bkt[s0 + i] >> 17], 1);
    __syncthreads();

    // exclusive scan of PADDED per-node sizes (pad to multiple of 8)
    int h0 = 0, h1 = 0;
    if (t < 98) { h0 = hist[2 * t]; h1 = hist[2 * t + 1]; }
    int p0 = (h0 + 7) & ~7;
    int p1 = (h1 + 7) & ~7;
    int sum = p0 + p1;
    int lane = t & 63, w = t >> 6;
    int s = sum;
#pragma unroll
    for (int d = 1; d < 64; d <<= 1) {
        int u = __shfl_up(s, d);
        if (lane >= d) s += u;
    }
    if (lane == 63) wt[w] = s;
    __syncthreads();
    int wbase = 0;
    for (int i = 0; i < w; i++) wbase += wt[i];
    int excl = wbase + s - sum;
    if (t < 98) {
        loff[2 * t] = excl;         loffB[2 * t] = excl;
        loff[2 * t + 1] = excl + p0; loffB[2 * t + 1] = excl + p0;
    }
    __syncthreads();

    for (int j = t; j < BKT_NODES; j += 256) {
        int n = b * BKT_NODES + j;
        if (n < N_NODES) {
            int c = hist[j];
            int o = b * CAPB + loff[j];
            off[n] = o;
            endp[n] = o + ((c + 7) & ~7);          // padded length
            dinv[n] = rsqrtf((float)(c + 1));
        }
    }
    __syncthreads();

    // scatter into padded staging
    for (int i = t; i < nE; i += 256) {
        unsigned pk = bkt[s0 + i];
        int dl = (int)(pk >> 17);
        int p = atomicAdd(&loff[dl], 1);
        csrS[p] = (int)(pk & 0x1FFFFu);
    }
    __syncthreads();

    // fill pad slots with dummy node id (zero feature row, dinv=0)
    for (int j = t; j < BKT_NODES; j += 256) {
        int c = hist[j];
        int bse = loffB[j];
        int pe = bse + ((c + 7) & ~7);
        for (int p = bse + c; p < pe; p++) csrS[p] = N_NODES;
    }
    __syncthreads();

    int padTot = wt[0] + wt[1] + wt[2] + wt[3];
    for (int i = t; i < padTot; i += 256) csr[b * CAPB + i] = csrS[i];
}

__device__ __forceinline__ void xw1_body(char* smem, int xb_id,
        const float* __restrict__ x, const float* __restrict__ W1,
        unsigned short* __restrict__ y1h) {
    unsigned short* Wb = (unsigned short*)smem;            // 16 KB
    unsigned short (*xbuf)[IN_F + 8] =
        (unsigned short (*)[IN_F + 8])(smem + 16384);      // 17.4 KB
    int tid = threadIdx.x;

    for (int i = tid; i < IN_F * HID_F; i += 256) {
        int k = i >> 6, n = i & 63;
        int kc = k >> 5, kw = k & 31;
        int nt = n >> 4, nl = n & 15;
        int quad = kw >> 3, j = kw & 7;
        Wb[(((kc * 4 + nt) * 64) + quad * 16 + nl) * 8 + j] = f2h(W1[i]);
    }

    int nodeBase = xb_id * XBM;
    {
        int snl = tid >> 2;
        int sk0 = (tid & 3) * 32;
        int n = nodeBase + snl;
#pragma unroll
        for (int kk = 0; kk < 32; kk += 4) {
            float4 v = make_float4(0.f, 0.f, 0.f, 0.f);
            if (n < N_NODES) v = *(const float4*)(x + (size_t)n * IN_F + sk0 + kk);
            ushort4 o;
            o.x = f2h(v.x); o.y = f2h(v.y); o.z = f2h(v.z); o.w = f2h(v.w);
            *(ushort4*)(&xbuf[snl][sk0 + kk]) = o;
        }
    }
    __syncthreads();

    int wave = tid >> 6, lane = tid & 63;
    int quad = lane >> 4, l15 = lane & 15;
    int rowBase = wave * 16;

    f4v acc[4];
#pragma unroll
    for (int i = 0; i < 4; i++) acc[i] = (f4v){0.f, 0.f, 0.f, 0.f};

#pragma unroll
    for (int kc = 0; kc < 4; kc++) {
        s8v a = *(const s8v*)(&xbuf[rowBase + l15][kc * 32 + quad * 8]);
#pragma unroll
        for (int nt = 0; nt < 4; nt++) {
            s8v b = *(const s8v*)(&Wb[((kc * 4 + nt) * 64 + lane) * 8]);
            acc[nt] = __builtin_amdgcn_mfma_f32_16x16x32_f16(a, b, acc[nt], 0, 0, 0);
        }
    }

    int n0 = nodeBase + rowBase + quad * 4;
#pragma unroll
    for (int nt = 0; nt < 4; nt++) {
#pragma unroll
        for (int r = 0; r < 4; r++) {
            int n = n0 + r;
            if (n < N_NODES + 1)   // row N_NODES: zero-staged x -> writes 0
                y1h[(size_t)n * HID_F + nt * 16 + l15] = f2h(acc[nt][r]);
        }
    }
}

__global__ __launch_bounds__(256) void sort_xw1_kernel(
        const int* __restrict__ cursor, const unsigned* __restrict__ bkt,
        int* __restrict__ csr, int* __restrict__ off, int* __restrict__ endp,
        float* __restrict__ dinv, const float* __restrict__ x,
        const float* __restrict__ W1, unsigned short* __restrict__ y1h) {
    __shared__ __align__(16) char smem[SMEM_BYTES];
    int b = blockIdx.x;
    if (b < NBKT)
        sort_body(smem, b, cursor, bkt, csr, off, endp, dinv);
    else
        xw1_body(smem, b - NBKT, x, W1, y1h);
}

// ---------------------------------------------------------------------------
// gather1 + y2 fused (round-10): round-6 gather1 body, then instead of
// writing hbuf to HBM, stage the identical H bits into a per-wave LDS slice
// and compute y2[n][c] = dv_n * sum_k h[k]*W2[k][c] with 32 fdot2 steps per
// lane (2 nodes x 32 cols = 64 lanes). W2 staged once per block as half2 in
// LDS (one entry __syncthreads; epilogue itself is wave-local, no sync).
// ---------------------------------------------------------------------------
__global__ __launch_bounds__(256) void gather1y2_kernel(
        const int* __restrict__ off, const int* __restrict__ endp,
        const int* __restrict__ csr, const unsigned short* __restrict__ y1h,
        const float* __restrict__ dinv, const float* __restrict__ b1,
        const float* __restrict__ W2, unsigned short* __restrict__ y2h) {
    __shared__ unsigned w2p[(HID_F / 2) * CLS_F];   // 1024 half2 = 4 KB
    __shared__ __align__(16) char hS[8 * 128];      // 8 nodes x 64 f16 = 1 KB

    int tid = threadIdx.x;
    // stage W2 as half2 pairs: w2p[k2*32+c] = (W2[2k2][c], W2[2k2+1][c])
    for (int i = tid; i < (HID_F / 2) * CLS_F; i += 256) {
        int k2 = i >> 5, c = i & 31;
        w2p[i] = (unsigned)packh2(W2[(2 * k2) * CLS_F + c],
                                  (2 * k2 + 1 < HID_F) ? W2[(2 * k2 + 1) * CLS_F + c] : 0.f);
    }
    __syncthreads();

    int wv = __builtin_amdgcn_readfirstlane(tid >> 6);
    int wave = blockIdx.x * 4 + wv;
    int nA = wave * 2, nB = nA + 1;
    int lane = tid & 63;
    int f = lane & 7;
    int g = lane >> 3;
    int fo = f * 16;

    int offA = off[nA], offB = off[nB];          // uniform -> s_load
    int lenA = endp[nA] - offA, lenB = endp[nB] - offB;   // multiples of 8
    int lmax = max(lenA, lenB);
    const int* pA = csr + offA + g;
    const int* pB = csr + offB + g;
    const char* yb = (const char*)y1h;

    float aA[8], aB[8];
#pragma unroll
    for (int j = 0; j < 8; j++) { aA[j] = 0.f; aB[j] = 0.f; }

    if (lmax > 0) {
        int rA = pA[0], rB = pB[0];
        int iA = (lenA > 0) ? rA : N_NODES;
        int iB = (lenB > 0) ? rB : N_NODES;
        float dvA = dinv[iA], dvB = dinv[iB];
        int4 vA = *(const int4*)(yb + (size_t)iA * 128 + fo);
        int4 vB = *(const int4*)(yb + (size_t)iB * 128 + fo);
        int rA1 = pA[8], rB1 = pB[8];            // prefetch (csr has slack)
        for (int t = 8; t < lmax; t += 8) {
            int inA = (t < lenA) ? rA1 : N_NODES;
            int inB = (t < lenB) ? rB1 : N_NODES;
            float ndvA = dinv[inA], ndvB = dinv[inB];
            int4 nxA = *(const int4*)(yb + (size_t)inA * 128 + fo);
            int4 nxB = *(const int4*)(yb + (size_t)inB * 128 + fo);
            rA1 = pA[t + 8]; rB1 = pB[t + 8];    // prefetch (slack-covered)
            mix8(aA, vA, dvA); mix8(aB, vB, dvB);
            vA = nxA; vB = nxB; dvA = ndvA; dvB = ndvB;
        }
        mix8(aA, vA, dvA); mix8(aB, vB, dvB);
    }

    // merged butterfly: level 32 cross-select, then 16, 8
    float c8[8];
#pragma unroll
    for (int j = 0; j < 8; j++) {
        float sel = (lane < 32) ? aB[j] : aA[j];
        float oth = __shfl_xor(sel, 32);
        c8[j] = ((lane < 32) ? aA[j] : aB[j]) + oth;
    }
#pragma unroll
    for (int m = 8; m <= 16; m <<= 1)
#pragma unroll
        for (int j = 0; j < 8; j++) c8[j] += __shfl_xor(c8[j], m);

    int node = (lane < 32) ? nA : nB;
    float dvA = dinv[nA], dvB = dinv[nB];
    float dvS = (lane < 32) ? dvA : dvB;

    // self loop: dv_d * xw[d]
    int4 sv = *(const int4*)(yb + (size_t)node * 128 + fo);
    mix8(c8, sv, dvS);

    float4 bl = *(const float4*)(b1 + 8 * f);
    float4 bh4 = *(const float4*)(b1 + 8 * f + 4);
    float bb[8] = {bl.x, bl.y, bl.z, bl.w, bh4.x, bh4.y, bh4.z, bh4.w};
    float h[8];
#pragma unroll
    for (int j = 0; j < 8; j++)
        h[j] = fmaxf(fmaf(c8[j], dvS, bb[j]), 0.f);
    int4 H;
    H.x = packh2(h[0], h[1]); H.y = packh2(h[2], h[3]);
    H.z = packh2(h[4], h[5]); H.w = packh2(h[6], h[7]);

    // stage H into this wave's LDS slice (same bits as the old hbuf write)
    int nl = wv * 2 + (lane >> 5);               // 0..7 within block
    if ((lane & 31) < 8)
        *(int4*)(hS + nl * 128 + fo) = H;
    // wave-local write->read: compiler-inserted lgkmcnt orders it; only this
    // wave's lanes read rows nl = wv*2 / wv*2+1.

    int c = lane & 31;
    const unsigned* hrow = (const unsigned*)(hS + nl * 128);
    float sum = 0.f;
#pragma unroll
    for (int k2 = 0; k2 < HID_F / 2; k2++)
        sum = fdot2acc(hrow[k2], w2p[k2 * 32 + c], sum);
    y2h[(size_t)node * CLS_F + c] = f2h(sum * dvS);

    // zero the dummy row N_NODES (read by gather2's padded edges)
    if (blockIdx.x == 0 && tid < 16)
        ((unsigned*)y2h)[(size_t)N_NODES * 16 + tid] = 0u;
}

// ---------------------------------------------------------------------------
// gather2 (round-6 verbatim): rows are 64 B (32 fp16) -> dwordx2 per lane,
// 8 lanes per edge. out = (sum y2[nbr] + y2[self]) * dinv + b2, f32.
// ---------------------------------------------------------------------------
__global__ __launch_bounds__(256) void gather2_kernel(const int* __restrict__ off,
                                                      const int* __restrict__ endp,
                                                      const int* __restrict__ csr,
                                                      const unsigned short* __restrict__ y2h,
                                                      const float* __restrict__ dinv,
                                                      const float* __restrict__ b2,
                                                      float* __restrict__ out) {
    int tid = threadIdx.x;
    int wv = __builtin_amdgcn_readfirstlane(tid >> 6);
    int wave = blockIdx.x * 4 + wv;
    int nA = wave * 2, nB = nA + 1;
    int lane = tid & 63;
    int f = lane & 7;
    int g = lane >> 3;
    int fo = f * 8;

    int offA = off[nA], offB = off[nB];
    int lenA = endp[nA] - offA, lenB = endp[nB] - offB;
    int lmax = max(lenA, lenB);
    const int* pA = csr + offA + g;
    const int* pB = csr + offB + g;
    const char* yb = (const char*)y2h;

    float aA[4], aB[4];
#pragma unroll
    for (int j = 0; j < 4; j++) { aA[j] = 0.f; aB[j] = 0.f; }

    if (lmax > 0) {
        int rA = pA[0], rB = pB[0];
        int iA = (lenA > 0) ? rA : N_NODES;
        int iB = (lenB > 0) ? rB : N_NODES;
        int2 vA = *(const int2*)(yb + (size_t)iA * 64 + fo);
        int2 vB = *(const int2*)(yb + (size_t)iB * 64 + fo);
        int rA1 = pA[8], rB1 = pB[8];
        for (int t = 8; t < lmax; t += 8) {
            int inA = (t < lenA) ? rA1 : N_NODES;
            int inB = (t < lenB) ? rB1 : N_NODES;
            int2 nxA = *(const int2*)(yb + (size_t)inA * 64 + fo);
            int2 nxB = *(const int2*)(yb + (size_t)inB * 64 + fo);
            rA1 = pA[t + 8]; rB1 = pB[t + 8];
            dot4(aA, vA); dot4(aB, vB);
            vA = nxA; vB = nxB;
        }
        dot4(aA, vA); dot4(aB, vB);
    }

    float c4[4];
#pragma unroll
    for (int j = 0; j < 4; j++) {
        float sel = (lane < 32) ? aB[j] : aA[j];
        float oth = __shfl_xor(sel, 32);
        c4[j] = ((lane < 32) ? aA[j] : aB[j]) + oth;
    }
#pragma unroll
    for (int m = 8; m <= 16; m <<= 1)
#pragma unroll
        for (int j = 0; j < 4; j++) c4[j] += __shfl_xor(c4[j], m);

    int node = (lane < 32) ? nA : nB;

    int2 sv = *(const int2*)(yb + (size_t)node * 64 + fo);
    dot4(c4, sv);

    float dvA = dinv[nA], dvB = dinv[nB];
    float dvS = (lane < 32) ? dvA : dvB;
    float4 b2v = *(const float4*)(b2 + 4 * f);
    float bbv[4] = {b2v.x, b2v.y, b2v.z, b2v.w};
    float4 o4;
    float* op = (float*)&o4;
#pragma unroll
    for (int j = 0; j < 4; j++)
        op[j] = fmaf(c4[j], dvS, bbv[j]);
    if ((lane & 31) < 8)
        *(float4*)(out + (size_t)node * CLS_F + f * 4) = o4;
}

extern "C" void kernel_launch(void* const* d_in, const int* in_sizes, int n_in,
                              void* d_out, int out_size, void* d_ws, size_t ws_size,
                              hipStream_t stream) {
    const float* x  = (const float*)d_in[0];
    const int*   ei = (const int*)d_in[1];
    // d_in[2] = edge_attr, unused by GCNConv
    const float* W1 = (const float*)d_in[3];
    const float* b1 = (const float*)d_in[4];
    const float* W2 = (const float*)d_in[5];
    const float* b2 = (const float*)d_in[6];
    float* out = (float*)d_out;

    const int* src = ei;
    const int* dst = ei + N_EDGES;

    char* ws = (char*)d_ws;
    size_t npad = ((size_t)(N_NODES + 1) * 4 + 255) / 256 * 256;   // 400128
    float* dinv   = (float*)ws;                       // npad (incl dummy slot)
    int*   cursor = (int*)(ws + npad);                // 2048
    int*   off    = (int*)(ws + npad + 2048);
    int*   endp   = (int*)(ws + 2 * npad + 2048);
    int*   csr    = (int*)(ws + 3 * npad + 2048);     // (NBKT+1)*CAPB ints (+slack)
    char*  p = (char*)csr + (size_t)(NBKT + 1) * CAPB * 4;
    unsigned* bkt = (unsigned*)p;                     // 8.4 MB (live during sort_xw1)
    p += (size_t)NBKT * CAPB_RAW * 4;
    unsigned short* y1h = (unsigned short*)p;         // (N+1)*64 fp16 = 12.8 MB (no alias)
    p += (size_t)(N_NODES + 1) * HID_F * 2;
    unsigned short* y2h = (unsigned short*)p;         // 6.4 MB

    dim3 blk(256);
    // zero dinv (incl dummy slot N) + cursor counts, one memset
    hipMemsetAsync(ws, 0, npad + 2048, stream);
    bucket_scatter_kernel<<<dim3(NBLK), blk, 0, stream>>>(src, dst, cursor, bkt);
    sort_xw1_kernel<<<dim3(NBKT + XW_BLOCKS), blk, 0, stream>>>(
        cursor, bkt, csr, off, endp, dinv, x, W1, y1h);
    gather1y2_kernel<<<dim3(N_NODES / 8), blk, 0, stream>>>(
        off, endp, csr, y1h, dinv, b1, W2, y2h);
    gather2_kernel<<<dim3(N_NODES / 8), blk, 0, stream>>>(off, endp, csr, y2h, dinv, b2, out);
}